// Round 4
// baseline (314.655 us; speedup 1.0000x reference)
//
#include <hip/hip_runtime.h>
#include <hip/hip_bf16.h>
#include <stdint.h>

// BlockedMLP: out = relu(bsr(relu(x@w1.T+b1))) @ w3.T + b3
// B=4096, D_IN=1024, H=4096, D_OUT=1024, BS=64

typedef __attribute__((ext_vector_type(4))) float f32x4;
typedef __attribute__((ext_vector_type(8))) __bf16 bf16x8;

#define DEV static __device__ __forceinline__

DEV ushort f2bf(float f) {
  union { float f; uint32_t u; } v; v.f = f;
  uint32_t r = v.u + 0x7fffu + ((v.u >> 16) & 1u);  // RNE
  return (ushort)(r >> 16);
}

DEV void gld_lds16(const void* g, void* l) {
  // async global->LDS, 16B/lane; LDS dest = wave-uniform base + lane*16
  __builtin_amdgcn_global_load_lds(
      (const __attribute__((address_space(1))) void*)g,
      (__attribute__((address_space(3))) void*)l, 16, 0, 0);
}

__global__ void cvt_kernel(const float* __restrict__ in, ushort* __restrict__ out, int n) {
  int i = (blockIdx.x * blockDim.x + threadIdx.x) * 4;
  if (i >= n) return;
  float4 v = *(const float4*)(in + i);
  ushort4 o;
  o.x = f2bf(v.x); o.y = f2bf(v.y); o.z = f2bf(v.z); o.w = f2bf(v.w);
  *(ushort4*)(out + i) = o;
}

// ---------------- dense GEMM (m97-structure, unchanged) ----------------
template <bool RELU, bool OUT_BF16>
__global__ __launch_bounds__(256)
void gemm_nt(const ushort* __restrict__ A, const ushort* __restrict__ W,
             const float* __restrict__ bias, void* __restrict__ Cv,
             int K, int lda, int ldw, int ldc) {
  __shared__ ushort As[128 * 64];
  __shared__ ushort Ws[128 * 64];
  const int tid = threadIdx.x;
  const int wid = tid >> 6, lane = tid & 63;
  const int wm = wid >> 1, wn = wid & 1;
  const int i0 = blockIdx.y * 128, j0 = blockIdx.x * 128;
  f32x4 acc[4][4] = {};

  const int lrow = lane >> 3;
  const int lcol = (lane & 7) * 16;

  for (int k0 = 0; k0 < K; k0 += 64) {
#pragma unroll
    for (int i = 0; i < 4; ++i) {
      int ch = wid * 4 + i;
      int row = ch * 8 + lrow;
      const char* ga = (const char*)A + ((size_t)(i0 + row) * lda + k0) * 2 + lcol;
      gld_lds16(ga, (char*)As + ch * 1024);
      const char* gw = (const char*)W + ((size_t)(j0 + row) * ldw + k0) * 2 + lcol;
      gld_lds16(gw, (char*)Ws + ch * 1024);
    }
    __syncthreads();
#pragma unroll
    for (int kk = 0; kk < 64; kk += 32) {
      const int cl = lane & 15;
      const int kg = kk + (lane >> 4) * 8;
      bf16x8 a[4], b[4];
#pragma unroll
      for (int m = 0; m < 4; ++m)
        a[m] = *(const bf16x8*)&As[(wm * 64 + m * 16 + cl) * 64 + kg];
#pragma unroll
      for (int n = 0; n < 4; ++n)
        b[n] = *(const bf16x8*)&Ws[(wn * 64 + n * 16 + cl) * 64 + kg];
#pragma unroll
      for (int m = 0; m < 4; ++m)
#pragma unroll
        for (int n = 0; n < 4; ++n)
          acc[m][n] = __builtin_amdgcn_mfma_f32_16x16x32_bf16(a[m], b[n], acc[m][n], 0, 0, 0);
    }
    __syncthreads();
  }

  const int cl = lane & 15, r4 = (lane >> 4) * 4;
#pragma unroll
  for (int n = 0; n < 4; ++n) {
    int col = j0 + wn * 64 + n * 16 + cl;
    float bv = bias ? bias[col] : 0.0f;
#pragma unroll
    for (int m = 0; m < 4; ++m) {
      int rowb = i0 + wm * 64 + m * 16 + r4;
#pragma unroll
      for (int r = 0; r < 4; ++r) {
        float v = acc[m][n][r] + bv;
        if (RELU) v = fmaxf(v, 0.0f);
        if (OUT_BF16)
          ((ushort*)Cv)[(size_t)(rowb + r) * ldc + col] = f2bf(v);
        else
          ((float*)Cv)[(size_t)(rowb + r) * ldc + col] = v;
      }
    }
  }
}

// ---- BSR GEMM v4: counted-vmcnt depth-2 pipeline, 8 waves, 3 LDS slots ----
// h2[:, br*64:+64] = relu( sum_{n in row br} h1[:, col[n]*64:+64] @ values[n]^T )
// 256x64 tile, 8 waves M-split (32x64 each, 2x4 frags).
// LDS: 3 slots x (A 32KB + V 8KB) = 120KB -> 1 block/CU (8 waves).
// Per iter: s_waitcnt vmcnt(5) [stage n landed, n+1 in flight] -> s_barrier ->
// issue stage(n+2) -> ds_read+MFMA(n). Never vmcnt(0) in steady state (T4).
// Hazard: stage(n+2) writes slot (n-1)%3, fully read before iter-n top barrier.
__global__ __launch_bounds__(512)
void bsr_gemm(const ushort* __restrict__ A, const ushort* __restrict__ V,
              const int* __restrict__ crow, const int* __restrict__ colind,
              ushort* __restrict__ C, int Hdim) {
  __shared__ ushort As[3][256 * 64];  // 3 x 32KB
  __shared__ ushort Vs[3][64 * 64];   // 3 x 8KB
  const int tid = threadIdx.x;
  const int wid = tid >> 6, lane = tid & 63;

  // tile-pinned XCD mapping (verified R3): XCD k owns batch tiles {k, k+8}
  const int bid = blockIdx.x;         // 0..1023
  const int xcd = bid & 7;
  const int j = bid >> 3;             // 0..127
  const int tile = xcd + 8 * (j & 1);
  const int br = j >> 1;              // 0..63, br-major
  const int i0 = tile * 256;

  f32x4 acc[2][4] = {};
  const int n0 = crow[br], n1 = crow[br + 1];
  const int nt = n1 - n0;

  const int lr = lane >> 3;                   // 0..7 row-in-chunk
  const int gsw = ((lane & 7) ^ lr) * 16;     // pre-swizzled source granule byte

  auto stage = [&](int slot, int n) {
    const int c = colind[n0 + n];
    const char* Abase = (const char*)A + ((size_t)i0 * Hdim + (size_t)c * 64) * 2;
#pragma unroll
    for (int i = 0; i < 4; ++i) {
      int ch = wid * 4 + i;          // 0..31
      int row = ch * 8 + lr;         // 0..255
      gld_lds16(Abase + (size_t)row * Hdim * 2 + gsw, (char*)As[slot] + ch * 1024);
    }
    const char* Vbase = (const char*)V + (size_t)(n0 + n) * 8192;
    gld_lds16(Vbase + (wid * 8 + lr) * 128 + gsw, (char*)Vs[slot] + wid * 1024);
  };

  auto compute = [&](int slot) {
#pragma unroll
    for (int kk = 0; kk < 64; kk += 32) {
      const int cl = lane & 15;
      const int kg = kk + (lane >> 4) * 8;
      const int kx = kg ^ ((cl & 7) << 3);   // row&7 == cl&7 for all frag rows
      bf16x8 a[2], b[4];
#pragma unroll
      for (int m = 0; m < 2; ++m)
        a[m] = *(const bf16x8*)&As[slot][(wid * 32 + m * 16 + cl) * 64 + kx];
#pragma unroll
      for (int nn = 0; nn < 4; ++nn)
        b[nn] = *(const bf16x8*)&Vs[slot][(nn * 16 + cl) * 64 + kx];
      __builtin_amdgcn_s_setprio(1);
#pragma unroll
      for (int m = 0; m < 2; ++m)
#pragma unroll
        for (int nn = 0; nn < 4; ++nn)
          acc[m][nn] = __builtin_amdgcn_mfma_f32_16x16x32_bf16(a[m], b[nn], acc[m][nn], 0, 0, 0);
      __builtin_amdgcn_s_setprio(0);
    }
  };

  // prologue: prefetch depth 2
  if (nt > 0) stage(0, 0);
  if (nt > 1) stage(1, 1);

  for (int n = 0; n < nt; ++n) {
    // wait for stage n (5 oldest loads); keep stage n+1's 5 loads in flight
    if (n + 1 < nt) asm volatile("s_waitcnt vmcnt(5)" ::: "memory");
    else            asm volatile("s_waitcnt vmcnt(0)" ::: "memory");
    asm volatile("s_barrier" ::: "memory");
    if (n + 2 < nt) stage((n + 2) % 3, n + 2);
    compute(n % 3);
  }

  const int cl = lane & 15, r4 = (lane >> 4) * 4;
#pragma unroll
  for (int nn = 0; nn < 4; ++nn) {
    int col = br * 64 + nn * 16 + cl;
#pragma unroll
    for (int m = 0; m < 2; ++m) {
      int rowb = i0 + wid * 32 + m * 16 + r4;
#pragma unroll
      for (int r = 0; r < 4; ++r) {
        float v = fmaxf(acc[m][nn][r], 0.0f);
        C[(size_t)(rowb + r) * Hdim + col] = f2bf(v);
      }
    }
  }
}

extern "C" void kernel_launch(void* const* d_in, const int* in_sizes, int n_in,
                              void* d_out, int out_size, void* d_ws, size_t ws_size,
                              hipStream_t stream) {
  const float* x    = (const float*)d_in[0];
  const float* w1   = (const float*)d_in[1];
  const float* b1   = (const float*)d_in[2];
  const float* vals = (const float*)d_in[3];
  const float* w3   = (const float*)d_in[4];
  const float* b3   = (const float*)d_in[5];
  const int* crow   = (const int*)d_in[6];
  const int* colind = (const int*)d_in[7];

  const int Bb = 4096, Din = 1024, H = 4096, Dout = 1024;
  const int nnzb = in_sizes[7];

  char* ws = (char*)d_ws;
  ushort* xb  = (ushort*)ws; ws += (size_t)Bb * Din * 2;
  ushort* w1b = (ushort*)ws; ws += (size_t)H * Din * 2;
  ushort* w3b = (ushort*)ws; ws += (size_t)Dout * H * 2;
  ushort* vb  = (ushort*)ws; ws += (size_t)nnzb * 64 * 64 * 2;
  ushort* h1b = (ushort*)ws; ws += (size_t)Bb * H * 2;
  ushort* h2b = (ushort*)ws; ws += (size_t)Bb * H * 2;

  auto cvt = [&](const float* src, ushort* dst, size_t n) {
    int blocks = (int)((n / 4 + 255) / 256);
    hipLaunchKernelGGL(cvt_kernel, dim3(blocks), dim3(256), 0, stream, src, dst, (int)n);
  };
  cvt(x, xb, (size_t)Bb * Din);
  cvt(w1, w1b, (size_t)H * Din);
  cvt(w3, w3b, (size_t)Dout * H);
  cvt(vals, vb, (size_t)nnzb * 4096);

  // stage 1: h1 = relu(x @ w1^T + b1)   [4096 x 4096] bf16
  hipLaunchKernelGGL((gemm_nt<true, true>), dim3(H / 128, Bb / 128), dim3(256), 0, stream,
                     xb, w1b, b1, (void*)h1b, Din, Din, Din, H);
  // stage 2: h2 = relu(bsr(h1))         [4096 x 4096] bf16
  hipLaunchKernelGGL(bsr_gemm, dim3((Bb / 256) * (H / 64)), dim3(512), 0, stream,
                     h1b, vb, crow, colind, h2b, H);
  // stage 3: out = h2 @ w3^T + b3       [4096 x 1024] f32
  hipLaunchKernelGGL((gemm_nt<false, false>), dim3(Dout / 128, Bb / 128), dim3(256), 0, stream,
                     h2b, w3b, b3, d_out, H, H, H, Dout);
}

// Round 5
// 295.577 us; speedup vs baseline: 1.0645x; 1.0645x over previous
//
#include <hip/hip_runtime.h>
#include <hip/hip_bf16.h>
#include <stdint.h>

// BlockedMLP: out = relu(bsr(relu(x@w1.T+b1))) @ w3.T + b3
// B=4096, D_IN=1024, H=4096, D_OUT=1024, BS=64

typedef __attribute__((ext_vector_type(4))) float f32x4;
typedef __attribute__((ext_vector_type(8))) __bf16 bf16x8;

#define DEV static __device__ __forceinline__

DEV ushort f2bf(float f) {
  union { float f; uint32_t u; } v; v.f = f;
  uint32_t r = v.u + 0x7fffu + ((v.u >> 16) & 1u);  // RNE
  return (ushort)(r >> 16);
}

DEV void gld_lds16(const void* g, void* l) {
  // async global->LDS, 16B/lane; LDS dest = wave-uniform base + lane*16
  __builtin_amdgcn_global_load_lds(
      (const __attribute__((address_space(1))) void*)g,
      (__attribute__((address_space(3))) void*)l, 16, 0, 0);
}

__global__ void cvt_kernel(const float* __restrict__ in, ushort* __restrict__ out, int n) {
  int i = (blockIdx.x * blockDim.x + threadIdx.x) * 4;
  if (i >= n) return;
  float4 v = *(const float4*)(in + i);
  ushort4 o;
  o.x = f2bf(v.x); o.y = f2bf(v.y); o.z = f2bf(v.z); o.w = f2bf(v.w);
  *(ushort4*)(out + i) = o;
}

// ---------------- dense GEMM (m97-structure, unchanged) ----------------
template <bool RELU, bool OUT_BF16>
__global__ __launch_bounds__(256)
void gemm_nt(const ushort* __restrict__ A, const ushort* __restrict__ W,
             const float* __restrict__ bias, void* __restrict__ Cv,
             int K, int lda, int ldw, int ldc) {
  __shared__ ushort As[128 * 64];
  __shared__ ushort Ws[128 * 64];
  const int tid = threadIdx.x;
  const int wid = tid >> 6, lane = tid & 63;
  const int wm = wid >> 1, wn = wid & 1;
  const int i0 = blockIdx.y * 128, j0 = blockIdx.x * 128;
  f32x4 acc[4][4] = {};

  const int lrow = lane >> 3;
  const int lcol = (lane & 7) * 16;

  for (int k0 = 0; k0 < K; k0 += 64) {
#pragma unroll
    for (int i = 0; i < 4; ++i) {
      int ch = wid * 4 + i;
      int row = ch * 8 + lrow;
      const char* ga = (const char*)A + ((size_t)(i0 + row) * lda + k0) * 2 + lcol;
      gld_lds16(ga, (char*)As + ch * 1024);
      const char* gw = (const char*)W + ((size_t)(j0 + row) * ldw + k0) * 2 + lcol;
      gld_lds16(gw, (char*)Ws + ch * 1024);
    }
    __syncthreads();
#pragma unroll
    for (int kk = 0; kk < 64; kk += 32) {
      const int cl = lane & 15;
      const int kg = kk + (lane >> 4) * 8;
      bf16x8 a[4], b[4];
#pragma unroll
      for (int m = 0; m < 4; ++m)
        a[m] = *(const bf16x8*)&As[(wm * 64 + m * 16 + cl) * 64 + kg];
#pragma unroll
      for (int n = 0; n < 4; ++n)
        b[n] = *(const bf16x8*)&Ws[(wn * 64 + n * 16 + cl) * 64 + kg];
#pragma unroll
      for (int m = 0; m < 4; ++m)
#pragma unroll
        for (int n = 0; n < 4; ++n)
          acc[m][n] = __builtin_amdgcn_mfma_f32_16x16x32_bf16(a[m], b[n], acc[m][n], 0, 0, 0);
    }
    __syncthreads();
  }

  const int cl = lane & 15, r4 = (lane >> 4) * 4;
#pragma unroll
  for (int n = 0; n < 4; ++n) {
    int col = j0 + wn * 64 + n * 16 + cl;
    float bv = bias ? bias[col] : 0.0f;
#pragma unroll
    for (int m = 0; m < 4; ++m) {
      int rowb = i0 + wm * 64 + m * 16 + r4;
#pragma unroll
      for (int r = 0; r < 4; ++r) {
        float v = acc[m][n][r] + bv;
        if (RELU) v = fmaxf(v, 0.0f);
        if (OUT_BF16)
          ((ushort*)Cv)[(size_t)(rowb + r) * ldc + col] = f2bf(v);
        else
          ((float*)Cv)[(size_t)(rowb + r) * ldc + col] = v;
      }
    }
  }
}

// ---- BSR GEMM v5: 2-phase-per-block interleaved schedule (m201-shape port) ----
// h2[:, br*64:+64] = relu( sum_{n in row br} h1[:, col[n]*64:+64] @ values[n]^T )
// 256x64 tile, 8 waves M-split (32x64 each, 2x4 frags of 16x16x32).
// LDS: 3 slots x (A 32KB + V 8KB) = 120KB, 1 block/CU (template-sanctioned).
// Per block n (slot s=n%3), staging block n+2 into slot (n+2)%3:
//   phase kk=0: ds_read a[2]+b[4] | issue 2 A-stage loads | bar | 8 MFMA | bar
//   phase kk=1: ds_read a[2]+b[4] | issue 2 A + 1 V stage  | bar | 8 MFMA
//   iter end:   s_waitcnt vmcnt(5)+s_barrier  (drain stage n+1, keep n+2 in flight)
// Never vmcnt(0) in steady state (T4); reads/stages interleave with MFMA (T3).
__global__ __launch_bounds__(512)
void bsr_gemm(const ushort* __restrict__ A, const ushort* __restrict__ V,
              const int* __restrict__ crow, const int* __restrict__ colind,
              ushort* __restrict__ C, int Hdim) {
  __shared__ ushort As[3][256 * 64];  // 3 x 32KB
  __shared__ ushort Vs[3][64 * 64];   // 3 x 8KB
  const int tid = threadIdx.x;
  const int wid = tid >> 6, lane = tid & 63;

  // tile-pinned XCD mapping (verified R3): XCD k owns batch tiles {k, k+8}
  const int bid = blockIdx.x;         // 0..1023
  const int xcd = bid & 7;
  const int j = bid >> 3;             // 0..127
  const int tile = xcd + 8 * (j & 1);
  const int br = j >> 1;              // 0..63, br-major
  const int i0 = tile * 256;

  f32x4 acc[2][4] = {};
  const int n0 = crow[br], n1 = crow[br + 1];
  const int nt = n1 - n0;

  const int lr = lane >> 3;                   // 0..7 row-in-chunk
  const int gsw = ((lane & 7) ^ lr) * 16;     // pre-swizzled source granule byte

  // per-wave stage loads per block: A chunks 0..3 (pairs) + 1 V chunk = 5 loads
  auto stageA2 = [&](int slot, int n, int pair) {
    const int c = colind[n0 + n];
    const char* Abase = (const char*)A + ((size_t)i0 * Hdim + (size_t)c * 64) * 2;
#pragma unroll
    for (int i = 0; i < 2; ++i) {
      int ch = wid * 4 + pair * 2 + i;  // 0..31
      int row = ch * 8 + lr;            // 0..255
      gld_lds16(Abase + (size_t)row * Hdim * 2 + gsw, (char*)As[slot] + ch * 1024);
    }
  };
  auto stageV1 = [&](int slot, int n) {
    const char* Vbase = (const char*)V + (size_t)(n0 + n) * 8192;
    gld_lds16(Vbase + (wid * 8 + lr) * 128 + gsw, (char*)Vs[slot] + wid * 1024);
  };

  const int cl = lane & 15;
  const int kbase = (lane >> 4) * 8;
  const int kxor = (cl & 7) << 3;  // granule swizzle (row&7 == cl&7 for frag rows)

  // prologue: prefetch depth 2
  stageA2(0, 0, 0); stageA2(0, 0, 1); stageV1(0, 0);
  if (nt > 1) {
    stageA2(1, 1, 0); stageA2(1, 1, 1); stageV1(1, 1);
    asm volatile("s_waitcnt vmcnt(5)\ns_barrier" ::: "memory");
  } else {
    asm volatile("s_waitcnt vmcnt(0)\ns_barrier" ::: "memory");
  }

  for (int n = 0; n < nt; ++n) {
    const int s = n % 3;
    const int s2 = (n + 2) % 3;
    const bool pf = (n + 2 < nt);
    const ushort* Asl = As[s];
    const ushort* Vsl = Vs[s];

#pragma unroll
    for (int kk = 0; kk < 2; ++kk) {
      const int kx = (kk * 32 + kbase) ^ kxor;
      bf16x8 a[2], b[4];
#pragma unroll
      for (int m = 0; m < 2; ++m)
        a[m] = *(const bf16x8*)&Asl[(wid * 32 + m * 16 + cl) * 64 + kx];
#pragma unroll
      for (int nn = 0; nn < 4; ++nn)
        b[nn] = *(const bf16x8*)&Vsl[(nn * 16 + cl) * 64 + kx];
      // interleave stage issues for block n+2
      if (pf) {
        stageA2(s2, n + 2, kk);
        if (kk == 1) stageV1(s2, n + 2);
      }
      asm volatile("s_barrier" ::: "memory");
      __builtin_amdgcn_s_setprio(1);
#pragma unroll
      for (int m = 0; m < 2; ++m)
#pragma unroll
        for (int nn = 0; nn < 4; ++nn)
          acc[m][nn] = __builtin_amdgcn_mfma_f32_16x16x32_bf16(a[m], b[nn], acc[m][nn], 0, 0, 0);
      __builtin_amdgcn_s_setprio(0);
      if (kk == 0) asm volatile("s_barrier" ::: "memory");
    }

    // iter boundary: ensure slot (n+1)%3 fully staged before next iter's reads
    if (pf)               asm volatile("s_waitcnt vmcnt(5)\ns_barrier" ::: "memory");
    else if (n + 1 < nt)  asm volatile("s_waitcnt vmcnt(0)\ns_barrier" ::: "memory");
  }

  const int r4 = (lane >> 4) * 4;
#pragma unroll
  for (int nn = 0; nn < 4; ++nn) {
    int col = br * 64 + nn * 16 + cl;
#pragma unroll
    for (int m = 0; m < 2; ++m) {
      int rowb = i0 + wid * 32 + m * 16 + r4;
#pragma unroll
      for (int r = 0; r < 4; ++r) {
        float v = fmaxf(acc[m][nn][r], 0.0f);
        C[(size_t)(rowb + r) * Hdim + col] = f2bf(v);
      }
    }
  }
}

extern "C" void kernel_launch(void* const* d_in, const int* in_sizes, int n_in,
                              void* d_out, int out_size, void* d_ws, size_t ws_size,
                              hipStream_t stream) {
  const float* x    = (const float*)d_in[0];
  const float* w1   = (const float*)d_in[1];
  const float* b1   = (const float*)d_in[2];
  const float* vals = (const float*)d_in[3];
  const float* w3   = (const float*)d_in[4];
  const float* b3   = (const float*)d_in[5];
  const int* crow   = (const int*)d_in[6];
  const int* colind = (const int*)d_in[7];

  const int Bb = 4096, Din = 1024, H = 4096, Dout = 1024;
  const int nnzb = in_sizes[7];

  char* ws = (char*)d_ws;
  ushort* xb  = (ushort*)ws; ws += (size_t)Bb * Din * 2;
  ushort* w1b = (ushort*)ws; ws += (size_t)H * Din * 2;
  ushort* w3b = (ushort*)ws; ws += (size_t)Dout * H * 2;
  ushort* vb  = (ushort*)ws; ws += (size_t)nnzb * 64 * 64 * 2;
  ushort* h1b = (ushort*)ws; ws += (size_t)Bb * H * 2;
  ushort* h2b = (ushort*)ws; ws += (size_t)Bb * H * 2;

  auto cvt = [&](const float* src, ushort* dst, size_t n) {
    int blocks = (int)((n / 4 + 255) / 256);
    hipLaunchKernelGGL(cvt_kernel, dim3(blocks), dim3(256), 0, stream, src, dst, (int)n);
  };
  cvt(x, xb, (size_t)Bb * Din);
  cvt(w1, w1b, (size_t)H * Din);
  cvt(w3, w3b, (size_t)Dout * H);
  cvt(vals, vb, (size_t)nnzb * 4096);

  // stage 1: h1 = relu(x @ w1^T + b1)   [4096 x 4096] bf16
  hipLaunchKernelGGL((gemm_nt<true, true>), dim3(H / 128, Bb / 128), dim3(256), 0, stream,
                     xb, w1b, b1, (void*)h1b, Din, Din, Din, H);
  // stage 2: h2 = relu(bsr(h1))         [4096 x 4096] bf16
  hipLaunchKernelGGL(bsr_gemm, dim3((Bb / 256) * (H / 64)), dim3(512), 0, stream,
                     h1b, vb, crow, colind, h2b, H);
  // stage 3: out = h2 @ w3^T + b3       [4096 x 1024] f32
  hipLaunchKernelGGL((gemm_nt<false, false>), dim3(Dout / 128, Bb / 128), dim3(256), 0, stream,
                     h2b, w3b, b3, d_out, H, H, H, Dout);
}